// Round 1
// baseline (224.134 us; speedup 1.0000x reference)
//
#include <hip/hip_runtime.h>

#define NBINS   20
#define NSETS   32          // replicated global accumulator slots (power of 2)
#define BLOCKS  2048
#define TPB     256
#define PACK    256.0f      // A = 256*cnt + sse ; per-thread cnt<=32, sse<32 -> exact decode

// ---------------- Pass 1: per-bin packed (count,sse) histogram ----------------
__global__ __launch_bounds__(TPB, 8)
void dwmse_pass1(const float* __restrict__ pred, const float* __restrict__ targ,
                 float* __restrict__ ws, int n, int setMask)
{
    // h[b*TPB + tid]: per-thread private accumulator. bank = tid%32 -> 2-way (free).
    __shared__ float h[NBINS * TPB];     // 20 KB -> 8 blocks/CU
    const int tid = threadIdx.x;

    #pragma unroll
    for (int b = 0; b < NBINS; ++b) h[b * TPB + tid] = 0.0f;
    __syncthreads();

    const int n4 = n >> 2;
    const float4* p4 = reinterpret_cast<const float4*>(pred);
    const float4* t4 = reinterpret_cast<const float4*>(targ);
    const int idx0    = blockIdx.x * TPB + tid;
    const int gstride = gridDim.x * TPB;

    int i = idx0;
    if (i < n4) {
        float4 p = p4[i];
        float4 t = t4[i];
        for (;;) {
            const int j = i + gstride;
            const bool more = (j < n4);
            float4 pn, tn;
            if (more) { pn = p4[j]; tn = t4[j]; }   // prefetch overlaps DS atomics below

            // ds_add_f32: no-return LDS atomic -> no lgkmcnt wait, no RMW chain.
            // Per-slot update order is per-wave in-order -> bitwise-identical to +=.
            {   float d = p.x - t.x; float a = fmaf(d, d, PACK);
                int b = min(max((int)(t.x * 20.0f), 0), NBINS - 1);
                atomicAdd(&h[b * TPB + tid], a); }
            {   float d = p.y - t.y; float a = fmaf(d, d, PACK);
                int b = min(max((int)(t.y * 20.0f), 0), NBINS - 1);
                atomicAdd(&h[b * TPB + tid], a); }
            {   float d = p.z - t.z; float a = fmaf(d, d, PACK);
                int b = min(max((int)(t.z * 20.0f), 0), NBINS - 1);
                atomicAdd(&h[b * TPB + tid], a); }
            {   float d = p.w - t.w; float a = fmaf(d, d, PACK);
                int b = min(max((int)(t.w * 20.0f), 0), NBINS - 1);
                atomicAdd(&h[b * TPB + tid], a); }

            if (!more) break;
            p = pn; t = tn; i = j;
        }
    }
    // scalar tail (empty for N = 2^24)
    for (int k = (n4 << 2) + idx0; k < n; k += gstride) {
        float t = targ[k];
        float d = pred[k] - t; float a = fmaf(d, d, PACK);
        int b = min(max((int)(t * 20.0f), 0), NBINS - 1);
        atomicAdd(&h[b * TPB + tid], a);
    }

    __syncthreads();

    // ---- epilogue: decode per thread, butterfly per wave, combine per block ----
    const int lane = tid & 63;
    const int wv   = tid >> 6;              // 4 waves
    float my_sse = 0.0f, my_cnt = 0.0f;

    for (int b = 0; b < NBINS; ++b) {
        float A = h[b * TPB + tid];
        float c = floorf(A * (1.0f / 256.0f));   // exact: sse < 256
        float s = A - 256.0f * c;
        #pragma unroll
        for (int m = 32; m; m >>= 1) { c += __shfl_xor(c, m); s += __shfl_xor(s, m); }
        if (lane == b) { my_cnt = c; my_sse = s; }
    }
    __syncthreads();                         // everyone done reading h -> safe to reuse
    if (lane < NBINS) {
        h[wv * 2 * NBINS + lane]         = my_sse;
        h[wv * 2 * NBINS + NBINS + lane] = my_cnt;
    }
    __syncthreads();
    if (tid < NBINS) {
        float ss = 0.0f, cc = 0.0f;
        #pragma unroll
        for (int w = 0; w < TPB / 64; ++w) {
            ss += h[w * 2 * NBINS + tid];
            cc += h[w * 2 * NBINS + NBINS + tid];
        }
        const int set = (int)(blockIdx.x) & setMask;
        unsafeAtomicAdd(&ws[set * 2 * NBINS + tid], ss);
        unsafeAtomicAdd(&ws[set * 2 * NBINS + NBINS + tid], cc);
    }
}

// ---------------- Pass 2: weights + final scalar ----------------
__global__ void dwmse_pass2(const float* __restrict__ ws, float* __restrict__ out,
                            int nsets, float inv_n)
{
    const int t = threadIdx.x;   // 64 threads = 1 wave
    float col = 0.0f;
    if (t < 2 * NBINS) {
        for (int s = 0; s < nsets; ++s) col += ws[s * 2 * NBINS + t];
    }
    // lanes 0..19 hold sse_b; counts live in lanes 20..39
    float sse = col;
    float cnt = __shfl(col, t + 20);

    float w = 0.0f;
    if (t < NBINS) {
        float c = fmaxf(cnt, 1.0f);
        w = __powf(c, -0.9f);
    }
    float s = w;
    #pragma unroll
    for (int off = 32; off > 0; off >>= 1) s += __shfl_down(s, off);
    s = __shfl(s, 0);

    float wb = (s > 0.0f) ? (w * (20.0f / s)) : w;
    wb = fmaxf(wb, 1.0f);

    float contrib = (t < NBINS) ? (wb * sse) : 0.0f;
    #pragma unroll
    for (int off = 32; off > 0; off >>= 1) contrib += __shfl_down(contrib, off);

    if (t == 0) out[0] = contrib * inv_n;
}

extern "C" void kernel_launch(void* const* d_in, const int* in_sizes, int n_in,
                              void* d_out, int out_size, void* d_ws, size_t ws_size,
                              hipStream_t stream)
{
    const float* pred = (const float*)d_in[0];
    const float* targ = (const float*)d_in[1];
    float*       out  = (float*)d_out;
    float*       ws   = (float*)d_ws;
    const int n = in_sizes[0];

    int nsets = NSETS;
    while ((size_t)nsets * 2 * NBINS * sizeof(float) > ws_size && nsets > 1) nsets >>= 1;

    hipMemsetAsync(d_ws, 0, (size_t)nsets * 2 * NBINS * sizeof(float), stream);
    dwmse_pass1<<<BLOCKS, TPB, 0, stream>>>(pred, targ, ws, n, nsets - 1);
    dwmse_pass2<<<1, 64, 0, stream>>>(ws, out, nsets, 1.0f / (float)n);
}

// Round 2
// 160.634 us; speedup vs baseline: 1.3953x; 1.3953x over previous
//
#include <hip/hip_runtime.h>

#define NBINS   20
#define NSETS   32          // replicated global accumulator slots (power of 2)
#define BLOCKS  2048
#define TPB     256
#define PACK    256.0f      // A = 256*cnt + sse ; per-thread cnt<=32, sse<32 -> exact decode

// ---------------- Pass 1: per-bin packed (count,sse) histogram ----------------
// Main loop keeps all 20 bin accumulators in REGISTERS (fully unrolled routing:
// cmp+cndmask+add per bin = pure VALU, no LDS round-trips, no chains).
// Epilogue: transpose through LDS (independent writes/reads, staggered banks),
// NOT the 20x12 chained-shuffle butterfly (that was ~46K LDS-pipe cycles/CU).
__global__ __launch_bounds__(TPB, 8)
void dwmse_pass1(const float* __restrict__ pred, const float* __restrict__ targ,
                 float* __restrict__ ws, int n, int setMask)
{
    __shared__ float h[NBINS * TPB];     // 20 KB -> 8 blocks/CU
    const int tid = threadIdx.x;

    float acc[NBINS];
    #pragma unroll
    for (int b = 0; b < NBINS; ++b) acc[b] = 0.0f;

    const int n4 = n >> 2;
    const float4* p4 = reinterpret_cast<const float4*>(pred);
    const float4* t4 = reinterpret_cast<const float4*>(targ);
    const int idx0    = blockIdx.x * TPB + tid;
    const int gstride = gridDim.x * TPB;

    int i = idx0;
    if (i < n4) {
        float4 p = p4[i];
        float4 t = t4[i];
        for (;;) {
            const int j = i + gstride;
            const bool more = (j < n4);
            float4 pn, tn;
            if (more) { pn = p4[j]; tn = t4[j]; }   // prefetch overlaps VALU below

            float d0 = p.x - t.x; float a0 = fmaf(d0, d0, PACK);
            float d1 = p.y - t.y; float a1 = fmaf(d1, d1, PACK);
            float d2 = p.z - t.z; float a2 = fmaf(d2, d2, PACK);
            float d3 = p.w - t.w; float a3 = fmaf(d3, d3, PACK);
            int b0 = min(max((int)(t.x * 20.0f), 0), NBINS - 1);
            int b1 = min(max((int)(t.y * 20.0f), 0), NBINS - 1);
            int b2 = min(max((int)(t.z * 20.0f), 0), NBINS - 1);
            int b3 = min(max((int)(t.w * 20.0f), 0), NBINS - 1);

            #pragma unroll
            for (int bb = 0; bb < NBINS; ++bb) {
                float add = ((bb == b0) ? a0 : 0.0f) + ((bb == b1) ? a1 : 0.0f)
                          + ((bb == b2) ? a2 : 0.0f) + ((bb == b3) ? a3 : 0.0f);
                acc[bb] += add;          // one add into acc per bin per iteration
            }

            if (!more) break;
            p = pn; t = tn; i = j;
        }
    }
    // scalar tail (empty for N = 2^24)
    for (int k = (n4 << 2) + idx0; k < n; k += gstride) {
        float t = targ[k];
        float d = pred[k] - t; float a = fmaf(d, d, PACK);
        int b = min(max((int)(t * 20.0f), 0), NBINS - 1);
        #pragma unroll
        for (int bb = 0; bb < NBINS; ++bb) acc[bb] += (bb == b) ? a : 0.0f;
    }

    // ---- decode per thread (exact: cnt<=32, sse<32), stage sse in LDS ----
    #pragma unroll
    for (int b = 0; b < NBINS; ++b) {
        float A = acc[b];
        float c = floorf(A * (1.0f / 256.0f));
        float s = A - 256.0f * c;
        h[b * TPB + tid] = s;            // phase A payload
        acc[b] = c;                      // keep counts for phase B
    }
    __syncthreads();

    // ---- phase A: 160 readers, each sums 32 consecutive (staggered) slots ----
    const int rbin = tid >> 3;           // bin for readers (tid < 160)
    const int rchk = tid & 7;            // chunk within bin
    float pA = 0.0f;
    if (tid < NBINS * 8) {
        const int base = rbin * TPB + rchk * 32;
        #pragma unroll
        for (int k = 0; k < 32; ++k)
            pA += h[base + ((k + tid) & 31)];   // stagger -> conflict-free
    }
    pA += __shfl_down(pA, 4);            // combine 8 chunks (aligned groups)
    pA += __shfl_down(pA, 2);
    pA += __shfl_down(pA, 1);
    const float blk_sse = pA;            // valid at rchk==0

    __syncthreads();                     // phase A reads done -> reuse h
    #pragma unroll
    for (int b = 0; b < NBINS; ++b) h[b * TPB + tid] = acc[b];
    __syncthreads();

    float pB = 0.0f;
    if (tid < NBINS * 8) {
        const int base = rbin * TPB + rchk * 32;
        #pragma unroll
        for (int k = 0; k < 32; ++k)
            pB += h[base + ((k + tid) & 31)];
    }
    pB += __shfl_down(pB, 4);
    pB += __shfl_down(pB, 2);
    pB += __shfl_down(pB, 1);

    if (tid < NBINS * 8 && rchk == 0) {
        const int set = (int)(blockIdx.x) & setMask;
        unsafeAtomicAdd(&ws[set * 2 * NBINS + rbin], blk_sse);
        unsafeAtomicAdd(&ws[set * 2 * NBINS + NBINS + rbin], pB);
    }
}

// ---------------- Pass 2: weights + final scalar ----------------
__global__ void dwmse_pass2(const float* __restrict__ ws, float* __restrict__ out,
                            int nsets, float inv_n)
{
    const int t = threadIdx.x;   // 64 threads = 1 wave
    float col = 0.0f;
    if (t < 2 * NBINS) {
        for (int s = 0; s < nsets; ++s) col += ws[s * 2 * NBINS + t];
    }
    // lanes 0..19 hold sse_b; counts live in lanes 20..39
    float sse = col;
    float cnt = __shfl(col, t + 20);

    float w = 0.0f;
    if (t < NBINS) {
        float c = fmaxf(cnt, 1.0f);
        w = __powf(c, -0.9f);
    }
    float s = w;
    #pragma unroll
    for (int off = 32; off > 0; off >>= 1) s += __shfl_down(s, off);
    s = __shfl(s, 0);

    float wb = (s > 0.0f) ? (w * (20.0f / s)) : w;
    wb = fmaxf(wb, 1.0f);

    float contrib = (t < NBINS) ? (wb * sse) : 0.0f;
    #pragma unroll
    for (int off = 32; off > 0; off >>= 1) contrib += __shfl_down(contrib, off);

    if (t == 0) out[0] = contrib * inv_n;
}

extern "C" void kernel_launch(void* const* d_in, const int* in_sizes, int n_in,
                              void* d_out, int out_size, void* d_ws, size_t ws_size,
                              hipStream_t stream)
{
    const float* pred = (const float*)d_in[0];
    const float* targ = (const float*)d_in[1];
    float*       out  = (float*)d_out;
    float*       ws   = (float*)d_ws;
    const int n = in_sizes[0];

    int nsets = NSETS;
    while ((size_t)nsets * 2 * NBINS * sizeof(float) > ws_size && nsets > 1) nsets >>= 1;

    hipMemsetAsync(d_ws, 0, (size_t)nsets * 2 * NBINS * sizeof(float), stream);
    dwmse_pass1<<<BLOCKS, TPB, 0, stream>>>(pred, targ, ws, n, nsets - 1);
    dwmse_pass2<<<1, 64, 0, stream>>>(ws, out, nsets, 1.0f / (float)n);
}

// Round 3
// 158.257 us; speedup vs baseline: 1.4163x; 1.0150x over previous
//
#include <hip/hip_runtime.h>

#define NBINS   20
#define NSETS   32          // replicated global accumulator slots (power of 2)
#define BLOCKS  2048
#define TPB     256
#define PACK    256.0f      // A = 256*cnt + sse ; per-thread cnt<=32, sse<32 -> exact decode

// ---------------- Pass 1: per-bin packed (count,sse) histogram ----------------
// Register-resident accumulators (r2 win) + prefetch-depth-2 software pipeline:
// loads for iter i+2 issue at the top of iter i; the register shift (which
// carries the vmcnt wait for the i+1 loads) happens AFTER the compute body,
// so each load gets ~2 compute bodies (~1080 cyc) of slack -> HBM latency
// hidden within a single wave, independent of occupancy.
__global__ __launch_bounds__(TPB, 8)
void dwmse_pass1(const float* __restrict__ pred, const float* __restrict__ targ,
                 float* __restrict__ ws, int n, int setMask)
{
    __shared__ float h[NBINS * TPB];     // 20 KB -> 8 blocks/CU
    const int tid = threadIdx.x;

    float acc[NBINS];
    #pragma unroll
    for (int b = 0; b < NBINS; ++b) acc[b] = 0.0f;

    const int n4 = n >> 2;
    const float4* p4 = reinterpret_cast<const float4*>(pred);
    const float4* t4 = reinterpret_cast<const float4*>(targ);
    const int idx0    = blockIdx.x * TPB + tid;
    const int gstride = gridDim.x * TPB;

    int i = idx0;
    if (i < n4) {
        float4 p  = p4[i];  float4 t  = t4[i];      // stage 0 (current)
        int  j  = i + gstride;
        bool mj = (j < n4);
        float4 pj, tj;
        if (mj) { pj = p4[j]; tj = t4[j]; }          // stage 1 (next)

        for (;;) {
            const int  k  = j + gstride;             // stage 2 (next-next)
            const bool mk = (k < n4);
            float4 pk, tk;
            if (mk) { pk = p4[k]; tk = t4[k]; }      // issue 2-ahead loads FIRST

            // ---- compute body on current (p,t): no waits needed here ----
            float d0 = p.x - t.x; float a0 = fmaf(d0, d0, PACK);
            float d1 = p.y - t.y; float a1 = fmaf(d1, d1, PACK);
            float d2 = p.z - t.z; float a2 = fmaf(d2, d2, PACK);
            float d3 = p.w - t.w; float a3 = fmaf(d3, d3, PACK);
            int b0 = min(max((int)(t.x * 20.0f), 0), NBINS - 1);
            int b1 = min(max((int)(t.y * 20.0f), 0), NBINS - 1);
            int b2 = min(max((int)(t.z * 20.0f), 0), NBINS - 1);
            int b3 = min(max((int)(t.w * 20.0f), 0), NBINS - 1);

            #pragma unroll
            for (int bb = 0; bb < NBINS; ++bb) {
                float add = ((bb == b0) ? a0 : 0.0f) + ((bb == b1) ? a1 : 0.0f)
                          + ((bb == b2) ? a2 : 0.0f) + ((bb == b3) ? a3 : 0.0f);
                acc[bb] += add;
            }

            if (!mj) break;
            // ---- shift-late: vmcnt wait for (pj,tj) lands here, after compute ----
            p  = pj; t  = tj;
            pj = pk; tj = tk;
            j = k; mj = mk;
        }
    }
    // scalar tail (empty for N = 2^24)
    for (int k = (n4 << 2) + idx0; k < n; k += gstride) {
        float t = targ[k];
        float d = pred[k] - t; float a = fmaf(d, d, PACK);
        int b = min(max((int)(t * 20.0f), 0), NBINS - 1);
        #pragma unroll
        for (int bb = 0; bb < NBINS; ++bb) acc[bb] += (bb == b) ? a : 0.0f;
    }

    // ---- decode per thread (exact: cnt<=32, sse<32), stage sse in LDS ----
    #pragma unroll
    for (int b = 0; b < NBINS; ++b) {
        float A = acc[b];
        float c = floorf(A * (1.0f / 256.0f));
        float s = A - 256.0f * c;
        h[b * TPB + tid] = s;            // phase A payload
        acc[b] = c;                      // keep counts for phase B
    }
    __syncthreads();

    // ---- phase A: 160 readers, each sums 32 consecutive (staggered) slots ----
    const int rbin = tid >> 3;           // bin for readers (tid < 160)
    const int rchk = tid & 7;            // chunk within bin
    float pA = 0.0f;
    if (tid < NBINS * 8) {
        const int base = rbin * TPB + rchk * 32;
        #pragma unroll
        for (int k = 0; k < 32; ++k)
            pA += h[base + ((k + tid) & 31)];   // stagger -> conflict-free
    }
    pA += __shfl_down(pA, 4);            // combine 8 chunks (aligned groups)
    pA += __shfl_down(pA, 2);
    pA += __shfl_down(pA, 1);
    const float blk_sse = pA;            // valid at rchk==0

    __syncthreads();                     // phase A reads done -> reuse h
    #pragma unroll
    for (int b = 0; b < NBINS; ++b) h[b * TPB + tid] = acc[b];
    __syncthreads();

    float pB = 0.0f;
    if (tid < NBINS * 8) {
        const int base = rbin * TPB + rchk * 32;
        #pragma unroll
        for (int k = 0; k < 32; ++k)
            pB += h[base + ((k + tid) & 31)];
    }
    pB += __shfl_down(pB, 4);
    pB += __shfl_down(pB, 2);
    pB += __shfl_down(pB, 1);

    if (tid < NBINS * 8 && rchk == 0) {
        const int set = (int)(blockIdx.x) & setMask;
        unsafeAtomicAdd(&ws[set * 2 * NBINS + rbin], blk_sse);
        unsafeAtomicAdd(&ws[set * 2 * NBINS + NBINS + rbin], pB);
    }
}

// ---------------- Pass 2: weights + final scalar ----------------
__global__ void dwmse_pass2(const float* __restrict__ ws, float* __restrict__ out,
                            int nsets, float inv_n)
{
    const int t = threadIdx.x;   // 64 threads = 1 wave
    float col = 0.0f;
    if (t < 2 * NBINS) {
        for (int s = 0; s < nsets; ++s) col += ws[s * 2 * NBINS + t];
    }
    // lanes 0..19 hold sse_b; counts live in lanes 20..39
    float sse = col;
    float cnt = __shfl(col, t + 20);

    float w = 0.0f;
    if (t < NBINS) {
        float c = fmaxf(cnt, 1.0f);
        w = __powf(c, -0.9f);
    }
    float s = w;
    #pragma unroll
    for (int off = 32; off > 0; off >>= 1) s += __shfl_down(s, off);
    s = __shfl(s, 0);

    float wb = (s > 0.0f) ? (w * (20.0f / s)) : w;
    wb = fmaxf(wb, 1.0f);

    float contrib = (t < NBINS) ? (wb * sse) : 0.0f;
    #pragma unroll
    for (int off = 32; off > 0; off >>= 1) contrib += __shfl_down(contrib, off);

    if (t == 0) out[0] = contrib * inv_n;
}

extern "C" void kernel_launch(void* const* d_in, const int* in_sizes, int n_in,
                              void* d_out, int out_size, void* d_ws, size_t ws_size,
                              hipStream_t stream)
{
    const float* pred = (const float*)d_in[0];
    const float* targ = (const float*)d_in[1];
    float*       out  = (float*)d_out;
    float*       ws   = (float*)d_ws;
    const int n = in_sizes[0];

    int nsets = NSETS;
    while ((size_t)nsets * 2 * NBINS * sizeof(float) > ws_size && nsets > 1) nsets >>= 1;

    hipMemsetAsync(d_ws, 0, (size_t)nsets * 2 * NBINS * sizeof(float), stream);
    dwmse_pass1<<<BLOCKS, TPB, 0, stream>>>(pred, targ, ws, n, nsets - 1);
    dwmse_pass2<<<1, 64, 0, stream>>>(ws, out, nsets, 1.0f / (float)n);
}